// Round 6
// baseline (812.670 us; speedup 1.0000x reference)
//
#include <hip/hip_runtime.h>
#include <hip/hip_bf16.h>
#include <stdint.h>

typedef unsigned short ushort_t;
typedef __bf16 bf16x8 __attribute__((ext_vector_type(8)));
typedef float f32x4 __attribute__((ext_vector_type(4)));

// ---------- helpers ----------
__device__ __forceinline__ ushort_t f2bf(float f) {
    union { float f; unsigned u; } v; v.f = f;
    unsigned u = v.u;
    unsigned r = u + 0x7fffu + ((u >> 16) & 1u);   // RNE
    return (ushort_t)(r >> 16);
}
__device__ __forceinline__ float bf2f(ushort_t h) {
    union { unsigned u; float f; } v; v.u = ((unsigned)h) << 16;
    return v.f;
}
__device__ __forceinline__ unsigned packbf(float a, float b) {
    return ((unsigned)f2bf(b) << 16) | f2bf(a);
}

#define GLDS16(gsrc, ldst)                                                    \
    __builtin_amdgcn_global_load_lds(                                         \
        (const __attribute__((address_space(1))) void*)(gsrc),                \
        (__attribute__((address_space(3))) void*)(ldst), 16, 0, 0)

// ---------- prep: W1 -> padded bf16 [512][800], W2 -> bf16, stats=0 ----------
__global__ __launch_bounds__(256) void prep_kernel(
    const float* __restrict__ W1, const float* __restrict__ W2,
    ushort_t* __restrict__ W1p, ushort_t* __restrict__ W2b,
    float* __restrict__ stats)
{
    int idx = blockIdx.x * 256 + threadIdx.x;
    if (idx < 512 * 800) {
        int n = idx / 800, k = idx - n * 800;
        W1p[idx] = (k < 784) ? f2bf(W1[n * 784 + k]) : (ushort_t)0;
    }
    if (idx < 128 * 512) W2b[idx] = f2bf(W2[idx]);
    if (idx == 0) stats[0] = 0.0f;
}

// ---------- fused: fc1+relu -> fc2+relu -> fc3 -> BCE / logits ----------
// 128 rows/block, 512 threads (8 waves), grid 544. Per nc-chunk (4 x 128
// cols of h1): 128x128 gemm1 (A inline fp32->bf16, reg-prefetched, padded
// LDS; B via async global_load_lds; dual 32-K panels -> 16 MFMA/barrier/
// wave), h1 relayed through LDS (stride 136, aliasing the staging buffers),
// gemm2 accumulated in registers with W2 fragments direct from global
// (131 KB, L2-hot for every block). h1/h2 never touch global memory.
// x rows stay L2-hot across the 4 nc passes (392 KB/block).
#define AS_STRIDE 36      // padded A staging stride (conflict-spread)
#define H_STRIDE  136     // padded h1/h2 relay stride

__global__ __launch_bounds__(512, 2) void fused_kernel(
    const float* __restrict__ x, const float* __restrict__ xu,
    const ushort_t* __restrict__ W1p, const ushort_t* __restrict__ W2b,
    const float* __restrict__ b1, const float* __restrict__ b2,
    const int* __restrict__ y, const float* __restrict__ W3,
    const float* __restrict__ b3,
    float* __restrict__ stats, float* __restrict__ logits_u)
{
    // staging: As0|As1 (128x36 each) + Bs0|Bs1 (128x32 each) = 17408 ushort,
    // exactly aliased by the h1/h2 relay hs (128 x 136).
    __shared__ ushort_t smem[17408];
    __shared__ float W3s[1280];
    __shared__ float b3s[10];
    __shared__ float red[8];

    ushort_t* As0 = smem;               // 128 x 36
    ushort_t* As1 = smem + 4608;        // 128 x 36
    ushort_t* Bs0 = smem + 9216;        // 128 x 32
    ushort_t* Bs1 = smem + 13312;       // 128 x 32
    ushort_t* hs  = smem;               // 128 x 136 relay (alias)

    const int tid = threadIdx.x;
    const int w = tid >> 6, lane = tid & 63;
    const int wm = w >> 2, wn = w & 3;          // wave grid 2 x 4, tile 64x32
    const int quad = lane >> 4, lc = lane & 15;
    const int row_in = lane >> 2;
    const int koff = (lane & 3) * 8;
    const int tile = blockIdx.x;
    const size_t m0 = (size_t)tile * 128;

    for (int i = tid; i < 1280; i += 512) W3s[i] = W3[i];
    if (tid < 10) b3s[tid] = b3[tid];

    // A staging geometry: 4 threads/row, 8 floats each (per panel)
    const int arow = tid >> 2;                  // 0..127
    const int akoff = (tid & 3) * 8;            // 0,8,16,24
    const size_t grow = m0 + arow;
    const float* asrc = (grow < 65536) ? (x + grow * 784)
                                       : (xu + (grow - 65536) * 784);
    ushort_t* adst0 = &As0[arow * AS_STRIDE + akoff];
    ushort_t* adst1 = &As1[arow * AS_STRIDE + akoff];

    f32x4 h2acc[4][2];
#pragma unroll
    for (int i = 0; i < 4; i++)
#pragma unroll
        for (int j = 0; j < 2; j++)
#pragma unroll
            for (int r = 0; r < 4; r++) h2acc[i][j][r] = 0.0f;

    for (int nc = 0; nc < 4; nc++) {
        f32x4 acc[4][2];
#pragma unroll
        for (int i = 0; i < 4; i++)
#pragma unroll
            for (int j = 0; j < 2; j++)
#pragma unroll
                for (int r = 0; r < 4; r++) acc[i][j][r] = 0.0f;

        // preload first two A chunks (k = akoff, 32+akoff; both valid)
        float4 p0a, p0b, p1a, p1b;
        {
            const float4* q0 = (const float4*)(asrc + akoff);
            p0a = q0[0]; p0b = q0[1];
            const float4* q1 = (const float4*)(asrc + 32 + akoff);
            p1a = q1[0]; p1b = q1[1];
        }

        // ---- gemm1 chunk: 128 x 128 out, K = 800, dual 32-panels ----
        for (int k0 = 0; k0 < 800; k0 += 64) {
            const bool has2 = (k0 + 32) < 800;
            // async B staging: 16 GLDS chunks (8 waves x 2)
#pragma unroll
            for (int c = 0; c < 2; c++) {
                int q = w * 2 + c;              // 0..15
                int p = q >> 3;                 // panel
                int rg = q & 7;                 // 16-row group
                if (p == 0 || has2) {
                    int row = rg * 16 + row_in;
                    const ushort_t* srcB =
                        W1p + (size_t)(nc * 128 + row) * 800 + k0 + p * 32 + koff;
                    GLDS16(srcB, (p ? Bs1 : Bs0) + rg * 512);
                }
            }
            // A staging from prefetched regs (zero-pad k >= 784)
            {
                uint4 u;
                if (k0 + akoff <= 776) {
                    u.x = packbf(p0a.x, p0a.y);
                    u.y = packbf(p0a.z, p0a.w);
                    u.z = packbf(p0b.x, p0b.y);
                    u.w = packbf(p0b.z, p0b.w);
                } else {
                    u = make_uint4(0, 0, 0, 0);
                }
                *(uint4*)adst0 = u;
            }
            if (has2) {
                uint4 u;
                if (k0 + 32 + akoff <= 776) {
                    u.x = packbf(p1a.x, p1a.y);
                    u.y = packbf(p1a.z, p1a.w);
                    u.z = packbf(p1b.x, p1b.y);
                    u.w = packbf(p1b.z, p1b.w);
                } else {
                    u = make_uint4(0, 0, 0, 0);
                }
                *(uint4*)adst1 = u;
            }
            // rolling prefetch for next iteration (overlaps barrier drain)
            {
                int kn0 = k0 + 64 + akoff;
                if (kn0 <= 776) {
                    const float4* q = (const float4*)(asrc + kn0);
                    p0a = q[0]; p0b = q[1];
                }
                int kn1 = k0 + 96 + akoff;
                if (kn1 <= 776) {
                    const float4* q = (const float4*)(asrc + kn1);
                    p1a = q[0]; p1b = q[1];
                }
            }
            __syncthreads();
            // compute panel 0
            {
                bf16x8 af[4], bfr[2];
#pragma unroll
                for (int i = 0; i < 4; i++)
                    af[i] = *(const bf16x8*)
                        &As0[(wm * 64 + i * 16 + lc) * AS_STRIDE + quad * 8];
#pragma unroll
                for (int j = 0; j < 2; j++)
                    bfr[j] = *(const bf16x8*)
                        &Bs0[(wn * 32 + j * 16 + lc) * 32 + quad * 8];
#pragma unroll
                for (int i = 0; i < 4; i++)
#pragma unroll
                    for (int j = 0; j < 2; j++)
                        acc[i][j] = __builtin_amdgcn_mfma_f32_16x16x32_bf16(
                            af[i], bfr[j], acc[i][j], 0, 0, 0);
            }
            if (has2) {
                bf16x8 af[4], bfr[2];
#pragma unroll
                for (int i = 0; i < 4; i++)
                    af[i] = *(const bf16x8*)
                        &As1[(wm * 64 + i * 16 + lc) * AS_STRIDE + quad * 8];
#pragma unroll
                for (int j = 0; j < 2; j++)
                    bfr[j] = *(const bf16x8*)
                        &Bs1[(wn * 32 + j * 16 + lc) * 32 + quad * 8];
#pragma unroll
                for (int i = 0; i < 4; i++)
#pragma unroll
                    for (int j = 0; j < 2; j++)
                        acc[i][j] = __builtin_amdgcn_mfma_f32_16x16x32_bf16(
                            af[i], bfr[j], acc[i][j], 0, 0, 0);
            }
            __syncthreads();
        }

        // ---- h1 chunk epilogue: bias+relu -> bf16 -> LDS relay ----
        {
            float bias[2];
#pragma unroll
            for (int j = 0; j < 2; j++)
                bias[j] = b1[nc * 128 + wn * 32 + j * 16 + lc];
#pragma unroll
            for (int i = 0; i < 4; i++) {
                int r0 = wm * 64 + i * 16 + quad * 4;
#pragma unroll
                for (int j = 0; j < 2; j++) {
                    int col = wn * 32 + j * 16 + lc;
#pragma unroll
                    for (int r = 0; r < 4; r++) {
                        float v = fmaxf(acc[i][j][r] + bias[j], 0.0f);
                        hs[(r0 + r) * H_STRIDE + col] = f2bf(v);
                    }
                }
            }
        }
        __syncthreads();

        // ---- gemm2 partial: 4 k-panels over this chunk's 128 cols;
        //      W2 fragments direct from global (L2-hot) ----
#pragma unroll
        for (int p = 0; p < 4; p++) {
            bf16x8 af[4], bfr[2];
#pragma unroll
            for (int i = 0; i < 4; i++)
                af[i] = *(const bf16x8*)
                    &hs[(wm * 64 + i * 16 + lc) * H_STRIDE + p * 32 + quad * 8];
#pragma unroll
            for (int j = 0; j < 2; j++)
                bfr[j] = *(const bf16x8*)
                    (W2b + (size_t)(wn * 32 + j * 16 + lc) * 512
                         + nc * 128 + p * 32 + quad * 8);
#pragma unroll
            for (int i = 0; i < 4; i++)
#pragma unroll
                for (int j = 0; j < 2; j++)
                    h2acc[i][j] = __builtin_amdgcn_mfma_f32_16x16x32_bf16(
                        af[i], bfr[j], h2acc[i][j], 0, 0, 0);
        }
        __syncthreads();   // protect hs before next chunk's staging reuse
    }

    // ---- h2 epilogue: bias+relu -> bf16 -> LDS ----
    {
        float bias[2];
#pragma unroll
        for (int j = 0; j < 2; j++) bias[j] = b2[wn * 32 + j * 16 + lc];
#pragma unroll
        for (int i = 0; i < 4; i++) {
            int r0 = wm * 64 + i * 16 + quad * 4;
#pragma unroll
            for (int j = 0; j < 2; j++) {
                int col = wn * 32 + j * 16 + lc;
#pragma unroll
                for (int r = 0; r < 4; r++) {
                    float v = fmaxf(h2acc[i][j][r] + bias[j], 0.0f);
                    hs[(r0 + r) * H_STRIDE + col] = f2bf(v);
                }
            }
        }
    }
    __syncthreads();

    // ---- fc3 + BCE / logits ----
    float bce_part = 0.0f;
    for (int o = tid; o < 1280; o += 512) {
        int r = o / 10, c = o - r * 10;
        size_t grw = m0 + r;
        float a = b3s[c];
        const ushort_t* hr = &hs[r * H_STRIDE];
        const float* wr = &W3s[c * 128];
#pragma unroll 8
        for (int k = 0; k < 128; k++) a += bf2f(hr[k]) * wr[k];
        if (grw < 65536) {
            float t = (y[grw] == c) ? 1.0f : 0.0f;
            bce_part += fmaxf(a, 0.0f) - a * t + log1pf(__expf(-fabsf(a)));
        } else {
            logits_u[(grw - 65536) * 10 + c] = a;
        }
    }
#pragma unroll
    for (int s = 32; s > 0; s >>= 1) bce_part += __shfl_down(bce_part, s, 64);
    if ((tid & 63) == 0) red[tid >> 6] = bce_part;
    __syncthreads();
    if (tid == 0) {
        float v = 0.0f;
#pragma unroll
        for (int i = 0; i < 8; i++) v += red[i];
        atomicAdd(stats, v);
    }
}

// ---------- finisher: semantic loss + output write ----------
// log_s[c] = S[c] + logsumexp_i(o_i[c]),  S[c] = sum_i logsigmoid(-o_i[c])
__global__ __launch_bounds__(640) void finisher_kernel(
    const float* __restrict__ logits_u, const float* __restrict__ stats,
    float* __restrict__ out)
{
    __shared__ float Rs[64][10];
    __shared__ float Rm[64][10];
    __shared__ float Scol[10], Mcol[10];

    const int tid = threadIdx.x;
    const int g = tid / 10, c = tid - g * 10;
    float s = 0.0f, m = -1e30f;
    for (int i = g; i < 4096; i += 64) {
        float o = logits_u[i * 10 + c];
        s += fminf(-o, 0.0f) - log1pf(__expf(-fabsf(o)));
        m = fmaxf(m, o);
    }
    Rs[g][c] = s;
    Rm[g][c] = m;
    __syncthreads();
    if (tid < 10) {
        float ss = 0.0f, mm = -1e30f;
        for (int gg = 0; gg < 64; gg++) {
            ss += Rs[gg][tid];
            mm = fmaxf(mm, Rm[gg][tid]);
        }
        Scol[tid] = ss;
        Mcol[tid] = mm;
    }
    __syncthreads();
    float e = 0.0f;
    float mm = Mcol[c];
    for (int i = g; i < 4096; i += 64)
        e += __expf(logits_u[i * 10 + c] - mm);
    Rs[g][c] = e;
    __syncthreads();
    if (tid == 0) {
        float sl = 0.0f;
        for (int cc = 0; cc < 10; cc++) {
            float ee = 0.0f;
            for (int gg = 0; gg < 64; gg++) ee += Rs[gg][cc];
            sl += -(Scol[cc] + Mcol[cc] + __logf(ee));
        }
        sl *= 0.1f;
        out[0] = stats[0] * (1.0f / (65536.0f * 10.0f));
        out[1] = sl;
    }
}

// ---------- launch ----------
extern "C" void kernel_launch(void* const* d_in, const int* in_sizes, int n_in,
                              void* d_out, int out_size, void* d_ws,
                              size_t ws_size, hipStream_t stream)
{
    const float* x  = (const float*)d_in[0];   // 65536x784
    const int*   y  = (const int*)d_in[1];     // 65536
    const float* xu = (const float*)d_in[2];   // 4096x784
    const float* W1 = (const float*)d_in[3];   // 512x784
    const float* b1 = (const float*)d_in[4];   // 512
    const float* W2 = (const float*)d_in[5];   // 128x512
    const float* b2 = (const float*)d_in[6];   // 128
    const float* W3 = (const float*)d_in[7];   // 10x128
    const float* b3 = (const float*)d_in[8];   // 10
    float* out = (float*)d_out;

    char* ws = (char*)d_ws;
    // layout (bytes), total ~1.1 MB:
    ushort_t* W1p      = (ushort_t*)(ws + 0);        // 819200
    ushort_t* W2b      = (ushort_t*)(ws + 819200);   // 131072 -> 950272
    float*    stats    = (float*)(ws + 950272);      // 256    -> 950528
    float*    logits_u = (float*)(ws + 950528);      // 163840 -> 1114368

    prep_kernel<<<1600, 256, 0, stream>>>(W1, W2, W1p, W2b, stats);
    fused_kernel<<<544, 512, 0, stream>>>(x, xu, W1p, W2b, b1, b2, y, W3, b3,
                                          stats, logits_u);
    finisher_kernel<<<1, 640, 0, stream>>>(logits_u, stats, out);
    (void)in_sizes; (void)n_in; (void)out_size; (void)ws_size;
}